// Round 2
// baseline (543.887 us; speedup 1.0000x reference)
//
#include <hip/hip_runtime.h>
#include <hip/hip_bf16.h>
#include <math.h>

// Problem constants (reference: B=8, S=1024, D=1024, E=8, F=2048, capacity 2 -> k=256)
#define B_   8
#define S_   1024
#define D_   1024
#define E_   8
#define F_   2048
#define KCAP 256

typedef __bf16 bf16x8 __attribute__((ext_vector_type(8)));
typedef float  floatx4 __attribute__((ext_vector_type(4)));

// ---- fp32 -> bf16 round-to-nearest-even (no NaN in this data) ----
__device__ __forceinline__ unsigned short f2b(float f) {
    union { float f; unsigned int u; } v; v.f = f;
    unsigned int u = v.u;
    u += 0x7fffu + ((u >> 16) & 1u);
    return (unsigned short)(u >> 16);
}

__device__ __forceinline__ void gl_lds16(const void* g, void* l) {
    __builtin_amdgcn_global_load_lds(
        (const __attribute__((address_space(1))) void*)g,
        (__attribute__((address_space(3))) void*)l, 16, 0, 0);
}

// ---------------- 1. cast x (fp32) -> bf16, vectorized ----------------
__global__ void cvt_x_kernel(const float* __restrict__ x, unsigned short* __restrict__ xb) {
    int i = blockIdx.x * 256 + threadIdx.x;           // grid sized exactly n/4
    float4 v = ((const float4*)x)[i];
    ushort4 o;
    o.x = f2b(v.x); o.y = f2b(v.y); o.z = f2b(v.z); o.w = f2b(v.w);
    ((ushort4*)xb)[i] = o;
}

// ---------------- 2. batched transpose + cast: in [E][R][C] fp32 -> out [E][C][R] bf16 ----------------
__global__ void transpose_cvt_kernel(const float* __restrict__ in, unsigned short* __restrict__ out,
                                     int R, int C) {
    __shared__ float tile[32][33];                    // +1 pad: no bank conflicts
    int e = blockIdx.z;
    int c0 = blockIdx.x * 32, r0 = blockIdx.y * 32;
    const float* ine = in + (size_t)e * R * C;
    unsigned short* oute = out + (size_t)e * R * C;
    int tx = threadIdx.x, ty = threadIdx.y;           // block (32, 8)
#pragma unroll
    for (int j = 0; j < 32; j += 8)
        tile[ty + j][tx] = ine[(size_t)(r0 + ty + j) * C + c0 + tx];
    __syncthreads();
#pragma unroll
    for (int j = 0; j < 32; j += 8)
        oute[(size_t)(c0 + ty + j) * R + r0 + tx] = f2b(tile[tx][ty + j]);
}

// ---------------- 3. router: logits + softmax, one wave per token, fp32 ----------------
// probs layout: [B][E][S]  (transposed for per-(b,e) top-k)
__global__ void router_kernel(const float* __restrict__ x, const float* __restrict__ cw,
                              float* __restrict__ probs) {
    int gid  = blockIdx.x * 256 + threadIdx.x;
    int wave = gid >> 6;
    int lane = gid & 63;
    int b = wave >> 10;                                // S_=1024
    int s = wave & (S_ - 1);
    const float* xrow = x + ((size_t)b * S_ + s) * D_;
    float acc[E_];
#pragma unroll
    for (int e = 0; e < E_; e++) acc[e] = 0.f;
    for (int i = lane; i < D_; i += 64) {
        float xv = xrow[i];
#pragma unroll
        for (int e = 0; e < E_; e++) acc[e] = fmaf(xv, cw[e * D_ + i], acc[e]);
    }
#pragma unroll
    for (int e = 0; e < E_; e++) {
        float v = acc[e];
#pragma unroll
        for (int off = 32; off >= 1; off >>= 1) v += __shfl_down(v, off, 64);
        acc[e] = v;
    }
    if (lane == 0) {
        float m = acc[0];
#pragma unroll
        for (int e = 1; e < E_; e++) m = fmaxf(m, acc[e]);
        float sum = 0.f;
#pragma unroll
        for (int e = 0; e < E_; e++) { acc[e] = __expf(acc[e] - m); sum += acc[e]; }
        float inv = 1.f / sum;
#pragma unroll
        for (int e = 0; e < E_; e++) probs[((size_t)b * E_ + e) * S_ + s] = acc[e] * inv;
    }
}

// ---------------- 4. top-k by rank counting (matches lax.top_k tie-break: value desc, index asc) ----------------
__global__ void topk_kernel(const float* __restrict__ probs, int* __restrict__ I, float* __restrict__ G) {
    int be = blockIdx.x;                               // one block per (b,e)
    const float* rowp = probs + (size_t)be * S_;
    __shared__ float p[S_];
    for (int i = threadIdx.x; i < S_; i += 256) p[i] = rowp[i];
    __syncthreads();
    int s0 = threadIdx.x, s1 = s0 + 256, s2 = s0 + 512, s3 = s0 + 768;
    float p0 = p[s0], p1 = p[s1], p2 = p[s2], p3 = p[s3];
    int r0 = 0, r1 = 0, r2 = 0, r3 = 0;
    for (int t = 0; t < S_; t++) {
        float pt = p[t];                               // LDS broadcast, conflict-free
        r0 += (pt > p0) || (pt == p0 && t < s0);
        r1 += (pt > p1) || (pt == p1 && t < s1);
        r2 += (pt > p2) || (pt == p2 && t < s2);
        r3 += (pt > p3) || (pt == p3 && t < s3);
    }
    int base = be * KCAP;
    if (r0 < KCAP) { I[base + r0] = s0; G[base + r0] = p0; }
    if (r1 < KCAP) { I[base + r1] = s1; G[base + r1] = p1; }
    if (r2 < KCAP) { I[base + r2] = s2; G[base + r2] = p2; }
    if (r3 < KCAP) { I[base + r3] = s3; G[base + r3] = p3; }
}

// ---------------- 5. GEMM1: H[be] = silu(gather(x, I[be]) @ w1[e]), bf16 MFMA ----------------
// A: gathered rows of xb [..][D], K-contig. B: w1t [E][F][D], K-contig. 128x128 tile, BK=32.
// Tile = 128 rows x 32 k x 2B = 8192 B; 256 threads x 16 B = 4096 B/sweep -> TWO sweeps per tile.
__global__ __launch_bounds__(256, 2) void gemm1_kernel(
    const unsigned short* __restrict__ xb,   // [B][S][D] bf16
    const unsigned short* __restrict__ w1t,  // [E][F][D] bf16
    const int* __restrict__ I,               // [B][E][KCAP]
    unsigned short* __restrict__ H)          // [B*E][KCAP][F] bf16
{
    const int be = blockIdx.x >> 5;
    const int t5 = blockIdx.x & 31;
    const int mt = t5 & 1;          // 2 m-tiles (256/128)
    const int nt = t5 >> 1;         // 16 n-tiles (2048/128)
    const int b  = be >> 3;
    const int e  = be & 7;
    const int tid = threadIdx.x;

    __shared__ __align__(16) unsigned short Asm[128 * 32];  // [m][k] row-major, 8KB
    __shared__ __align__(16) unsigned short Bsm[128 * 32];  // [n][k] row-major, 8KB
    __shared__ unsigned int ArowS[128];

    if (tid < 128) {
        int tok = I[(size_t)be * KCAP + mt * 128 + tid];
        ArowS[tid] = (unsigned)((b * S_ + tok) * D_);
    }
    __syncthreads();

    const int row = tid >> 2;       // staging row 0..63 (sweep 0); +64 (sweep 1)
    const int seg = tid & 3;        // 16B segment within 64B row-slab
    const unsigned aoff0 = ArowS[row]      + seg * 8;
    const unsigned aoff1 = ArowS[row + 64] + seg * 8;
    const size_t   boff0 = ((size_t)e * F_ + nt * 128 + row) * D_ + seg * 8;
    const size_t   boff1 = boff0 + (size_t)64 * D_;

    const int lane = tid & 63;
    const int wv   = tid >> 6;
    const int wm   = (wv & 1) * 64;
    const int wn   = (wv >> 1) * 64;
    const int l15  = lane & 15;
    const int quad = lane >> 4;

    int aoffs[4], boffs[4];
#pragma unroll
    for (int i = 0; i < 4; i++) {
        aoffs[i] = (wm + i * 16 + l15) * 32 + quad * 8;
        boffs[i] = (wn + i * 16 + l15) * 32 + quad * 8;
    }

    floatx4 acc[4][4];
#pragma unroll
    for (int i = 0; i < 4; i++)
#pragma unroll
        for (int j = 0; j < 4; j++) acc[i][j] = (floatx4){0.f, 0.f, 0.f, 0.f};

    for (int k0 = 0; k0 < D_; k0 += 32) {
        gl_lds16(xb  + aoff0 + k0, &Asm[tid * 8]);
        gl_lds16(xb  + aoff1 + k0, &Asm[2048 + tid * 8]);
        gl_lds16(w1t + boff0 + k0, &Bsm[tid * 8]);
        gl_lds16(w1t + boff1 + k0, &Bsm[2048 + tid * 8]);
        __syncthreads();                        // drains vmcnt: LDS tiles complete
        bf16x8 af[4], bfr[4];
#pragma unroll
        for (int i = 0; i < 4; i++) {
            af[i]  = *(const bf16x8*)&Asm[aoffs[i]];
            bfr[i] = *(const bf16x8*)&Bsm[boffs[i]];
        }
#pragma unroll
        for (int i = 0; i < 4; i++)
#pragma unroll
            for (int j = 0; j < 4; j++)
                acc[i][j] = __builtin_amdgcn_mfma_f32_16x16x32_bf16(af[i], bfr[j], acc[i][j], 0, 0, 0);
        __syncthreads();                        // all waves done reading before next stage
    }

    // epilogue: silu -> H (bf16). C/D layout: row = quad*4+r, col = lane&15 (m89-verified)
    unsigned short* Hbe = H + (size_t)be * KCAP * F_;
#pragma unroll
    for (int i = 0; i < 4; i++) {
#pragma unroll
        for (int r = 0; r < 4; r++) {
            int m = mt * 128 + wm + i * 16 + quad * 4 + r;
            unsigned short* hrow = Hbe + (size_t)m * F_ + nt * 128;
#pragma unroll
            for (int j = 0; j < 4; j++) {
                float v = acc[i][j][r];
                float sv = v / (1.f + __expf(-v));
                hrow[wn + j * 16 + l15] = f2b(sv);
            }
        }
    }
}

// ---------------- 6. GEMM2: out[b, I[be,m], :] += G[be,m] * (H[be] @ w2[e]) ----------------
__global__ __launch_bounds__(256, 2) void gemm2_kernel(
    const unsigned short* __restrict__ H,    // [B*E][KCAP][F] bf16
    const unsigned short* __restrict__ w2t,  // [E][D][F] bf16
    const int* __restrict__ I,
    const float* __restrict__ G,
    float* __restrict__ out)                 // [B][S][D] fp32, pre-zeroed
{
    const int be = blockIdx.x >> 4;
    const int t4 = blockIdx.x & 15;
    const int mt = t4 & 1;          // 2 m-tiles
    const int nt = t4 >> 1;         // 8 n-tiles (1024/128)
    const int b  = be >> 3;
    const int e  = be & 7;
    const int tid = threadIdx.x;

    __shared__ __align__(16) unsigned short Asm[128 * 32];
    __shared__ __align__(16) unsigned short Bsm[128 * 32];
    __shared__ unsigned int OrowS[128];
    __shared__ float Gs[128];

    if (tid < 128) {
        int tok = I[(size_t)be * KCAP + mt * 128 + tid];
        OrowS[tid] = (unsigned)((b * S_ + tok) * D_);
        Gs[tid] = G[(size_t)be * KCAP + mt * 128 + tid];
    }
    __syncthreads();

    const int row = tid >> 2;
    const int seg = tid & 3;
    const size_t aoff0 = ((size_t)be * KCAP + mt * 128 + row) * F_ + seg * 8;
    const size_t aoff1 = aoff0 + (size_t)64 * F_;
    const size_t boff0 = ((size_t)e * D_ + nt * 128 + row) * F_ + seg * 8;
    const size_t boff1 = boff0 + (size_t)64 * F_;

    const int lane = tid & 63;
    const int wv   = tid >> 6;
    const int wm   = (wv & 1) * 64;
    const int wn   = (wv >> 1) * 64;
    const int l15  = lane & 15;
    const int quad = lane >> 4;

    int aoffs[4], boffs[4];
#pragma unroll
    for (int i = 0; i < 4; i++) {
        aoffs[i] = (wm + i * 16 + l15) * 32 + quad * 8;
        boffs[i] = (wn + i * 16 + l15) * 32 + quad * 8;
    }

    floatx4 acc[4][4];
#pragma unroll
    for (int i = 0; i < 4; i++)
#pragma unroll
        for (int j = 0; j < 4; j++) acc[i][j] = (floatx4){0.f, 0.f, 0.f, 0.f};

    for (int k0 = 0; k0 < F_; k0 += 32) {
        gl_lds16(H   + aoff0 + k0, &Asm[tid * 8]);
        gl_lds16(H   + aoff1 + k0, &Asm[2048 + tid * 8]);
        gl_lds16(w2t + boff0 + k0, &Bsm[tid * 8]);
        gl_lds16(w2t + boff1 + k0, &Bsm[2048 + tid * 8]);
        __syncthreads();
        bf16x8 af[4], bfr[4];
#pragma unroll
        for (int i = 0; i < 4; i++) {
            af[i]  = *(const bf16x8*)&Asm[aoffs[i]];
            bfr[i] = *(const bf16x8*)&Bsm[boffs[i]];
        }
#pragma unroll
        for (int i = 0; i < 4; i++)
#pragma unroll
            for (int j = 0; j < 4; j++)
                acc[i][j] = __builtin_amdgcn_mfma_f32_16x16x32_bf16(af[i], bfr[j], acc[i][j], 0, 0, 0);
        __syncthreads();
    }

    // epilogue: weighted atomic scatter-add (token may be chosen by several experts)
#pragma unroll
    for (int i = 0; i < 4; i++) {
#pragma unroll
        for (int r = 0; r < 4; r++) {
            int m = wm + i * 16 + quad * 4 + r;           // local row in this 128-tile
            float g = Gs[m];
            float* orow = out + OrowS[m] + nt * 128;
#pragma unroll
            for (int j = 0; j < 4; j++)
                atomicAdd(orow + wn + j * 16 + l15, g * acc[i][j][r]);
        }
    }
}

// ---------------- launch ----------------
extern "C" void kernel_launch(void* const* d_in, const int* in_sizes, int n_in,
                              void* d_out, int out_size, void* d_ws, size_t ws_size,
                              hipStream_t stream) {
    const float* x  = (const float*)d_in[0];
    const float* cw = (const float*)d_in[1];
    const float* w1 = (const float*)d_in[2];
    const float* w2 = (const float*)d_in[3];
    float* out = (float*)d_out;

    // workspace layout (bytes), total 117,833,728 (small buffers first; wT shared
    // between w1t (gemm1) and w2t (gemm2) -- transpose of w2 runs AFTER gemm1):
    char* ws = (char*)d_ws;
    float*          probs = (float*)(ws);                        //   0.26 MB  [B][E][S]
    int*            Ibuf  = (int*)(ws + 262144);                 //  64 KB     [B][E][256]
    float*          Gbuf  = (float*)(ws + 327680);               //  64 KB
    unsigned short* xb    = (unsigned short*)(ws + 393216);      //  16.78 MB  x bf16
    unsigned short* wT    = (unsigned short*)(ws + 17170432);    //  33.55 MB  [E][F][D] then [E][D][F]
    unsigned short* Hbuf  = (unsigned short*)(ws + 50724864);    //  67.11 MB  [B*E][256][F]

    hipMemsetAsync(d_out, 0, (size_t)out_size * sizeof(float), stream);

    cvt_x_kernel<<<(B_ * S_ * D_) / 4 / 256, 256, 0, stream>>>(x, xb);
    router_kernel<<<(B_ * S_ * 64) / 256, 256, 0, stream>>>(x, cw, probs);
    topk_kernel<<<B_ * E_, 256, 0, stream>>>(probs, Ibuf, Gbuf);
    transpose_cvt_kernel<<<dim3(F_ / 32, D_ / 32, E_), dim3(32, 8), 0, stream>>>(w1, wT, D_, F_);
    gemm1_kernel<<<B_ * E_ * 2 * (F_ / 128), 256, 0, stream>>>(xb, wT, Ibuf, Hbuf);
    transpose_cvt_kernel<<<dim3(D_ / 32, F_ / 32, E_), dim3(32, 8), 0, stream>>>(w2, wT, F_, D_);
    gemm2_kernel<<<B_ * E_ * 2 * (D_ / 128), 256, 0, stream>>>(Hbuf, wT, Ibuf, Gbuf, out);
}

// Round 3
// 511.386 us; speedup vs baseline: 1.0636x; 1.0636x over previous
//
#include <hip/hip_runtime.h>
#include <hip/hip_bf16.h>
#include <math.h>

// Problem constants (reference: B=8, S=1024, D=1024, E=8, F=2048, capacity 2 -> k=256)
#define B_   8
#define S_   1024
#define D_   1024
#define E_   8
#define F_   2048
#define KCAP 256

typedef __bf16 bf16x8 __attribute__((ext_vector_type(8)));
typedef float  floatx4 __attribute__((ext_vector_type(4)));
typedef unsigned short ushortx8 __attribute__((ext_vector_type(8)));

// ---- fp32 -> bf16 round-to-nearest-even (no NaN in this data) ----
__device__ __forceinline__ unsigned short f2b(float f) {
    union { float f; unsigned int u; } v; v.f = f;
    unsigned int u = v.u;
    u += 0x7fffu + ((u >> 16) & 1u);
    return (unsigned short)(u >> 16);
}
__device__ __forceinline__ float b2f(unsigned short u) {
    union { unsigned int u; float f; } v; v.u = ((unsigned)u) << 16; return v.f;
}

__device__ __forceinline__ void gl_lds16(const void* g, void* l) {
    __builtin_amdgcn_global_load_lds(
        (const __attribute__((address_space(1))) void*)g,
        (__attribute__((address_space(3))) void*)l, 16, 0, 0);
}

// ---------------- 1. router: logits + softmax (fp32) + fused x->bf16 cast ----------------
// probs layout: [B][E][S] (transposed for per-(b,e) top-k). One wave per token.
__global__ void router_kernel(const float* __restrict__ x, const float* __restrict__ cw,
                              float* __restrict__ probs, unsigned short* __restrict__ xb) {
    int gid  = blockIdx.x * 256 + threadIdx.x;
    int wave = gid >> 6;
    int lane = gid & 63;
    int b = wave >> 10;                                // S_=1024
    int s = wave & (S_ - 1);
    const float* xrow = x + ((size_t)b * S_ + s) * D_;
    unsigned short* xbrow = xb + ((size_t)b * S_ + s) * D_;
    float acc[E_];
#pragma unroll
    for (int e = 0; e < E_; e++) acc[e] = 0.f;
    for (int i = lane; i < D_; i += 64) {
        float xv = xrow[i];
        xbrow[i] = f2b(xv);                            // fused cast (coalesced 2B stores)
#pragma unroll
        for (int e = 0; e < E_; e++) acc[e] = fmaf(xv, cw[e * D_ + i], acc[e]);
    }
#pragma unroll
    for (int e = 0; e < E_; e++) {
        float v = acc[e];
#pragma unroll
        for (int off = 32; off >= 1; off >>= 1) v += __shfl_down(v, off, 64);
        acc[e] = v;
    }
    if (lane == 0) {
        float m = acc[0];
#pragma unroll
        for (int e = 1; e < E_; e++) m = fmaxf(m, acc[e]);
        float sum = 0.f;
#pragma unroll
        for (int e = 0; e < E_; e++) { acc[e] = __expf(acc[e] - m); sum += acc[e]; }
        float inv = 1.f / sum;
#pragma unroll
        for (int e = 0; e < E_; e++) probs[((size_t)b * E_ + e) * S_ + s] = acc[e] * inv;
    }
}

// ---------------- 2. top-k by rank counting (matches lax.top_k tie-break: value desc, index asc) --------
__global__ void topk_kernel(const float* __restrict__ probs, int* __restrict__ I, float* __restrict__ G) {
    int be = blockIdx.x;                               // one block per (b,e)
    const float* rowp = probs + (size_t)be * S_;
    __shared__ float p[S_];
    for (int i = threadIdx.x; i < S_; i += 256) p[i] = rowp[i];
    __syncthreads();
    int s0 = threadIdx.x, s1 = s0 + 256, s2 = s0 + 512, s3 = s0 + 768;
    float p0 = p[s0], p1 = p[s1], p2 = p[s2], p3 = p[s3];
    int r0 = 0, r1 = 0, r2 = 0, r3 = 0;
    for (int t = 0; t < S_; t++) {
        float pt = p[t];                               // LDS broadcast, conflict-free
        r0 += (pt > p0) || (pt == p0 && t < s0);
        r1 += (pt > p1) || (pt == p1 && t < s1);
        r2 += (pt > p2) || (pt == p2 && t < s2);
        r3 += (pt > p3) || (pt == p3 && t < s3);
    }
    int base = be * KCAP;
    if (r0 < KCAP) { I[base + r0] = s0; G[base + r0] = p0; }
    if (r1 < KCAP) { I[base + r1] = s1; G[base + r1] = p1; }
    if (r2 < KCAP) { I[base + r2] = s2; G[base + r2] = p2; }
    if (r3 < KCAP) { I[base + r3] = s3; G[base + r3] = p3; }
}

// ---------------- 3. inverse dispatch map: Pmap[b][s][e] = slot+1 (0 = not chosen) ----------------
__global__ void pmap_build_kernel(const int* __restrict__ I, unsigned short* __restrict__ Pmap) {
    int be = blockIdx.x;                               // 64 blocks x 256 threads
    int slot = threadIdx.x;
    int b = be >> 3, e = be & 7;
    int tok = I[be * KCAP + slot];
    Pmap[((size_t)(b * S_ + tok)) * E_ + e] = (unsigned short)(slot + 1);
}

// ---------------- 4. batched transpose + cast: in [E][R][C] fp32 -> out [E][C][R] bf16 ----------------
__global__ void transpose_cvt_kernel(const float* __restrict__ in, unsigned short* __restrict__ out,
                                     int R, int C) {
    __shared__ float tile[32][33];                    // +1 pad: no bank conflicts
    int e = blockIdx.z;
    int c0 = blockIdx.x * 32, r0 = blockIdx.y * 32;
    const float* ine = in + (size_t)e * R * C;
    unsigned short* oute = out + (size_t)e * R * C;
    int tx = threadIdx.x, ty = threadIdx.y;           // block (32, 8)
#pragma unroll
    for (int j = 0; j < 32; j += 8)
        tile[ty + j][tx] = ine[(size_t)(r0 + ty + j) * C + c0 + tx];
    __syncthreads();
#pragma unroll
    for (int j = 0; j < 32; j += 8)
        oute[(size_t)(c0 + ty + j) * R + r0 + tx] = f2b(tile[tx][ty + j]);
}

// ---------------- 5. GEMM1: H[be] = silu(gather(x, I[be]) @ w1[e]), bf16 MFMA ----------------
// Tile = 128 rows x 32 k x 2B = 8192 B; 256 threads x 16 B = 4096 B/sweep -> TWO sweeps per tile.
// launch_bounds(256,4): VGPR+AGPR ~120 <= 128 -> 4 blocks/CU (latency cover for the barrier drain).
__global__ __launch_bounds__(256, 4) void gemm1_kernel(
    const unsigned short* __restrict__ xb,   // [B][S][D] bf16
    const unsigned short* __restrict__ w1t,  // [E][F][D] bf16
    const int* __restrict__ I,               // [B][E][KCAP]
    unsigned short* __restrict__ H)          // [B*E][KCAP][F] bf16
{
    const int be = blockIdx.x >> 5;
    const int t5 = blockIdx.x & 31;
    const int mt = t5 & 1;          // 2 m-tiles (256/128)
    const int nt = t5 >> 1;         // 16 n-tiles (2048/128)
    const int b  = be >> 3;
    const int e  = be & 7;
    const int tid = threadIdx.x;

    __shared__ __align__(16) unsigned short Asm[128 * 32];  // [m][k] row-major, 8KB
    __shared__ __align__(16) unsigned short Bsm[128 * 32];  // [n][k] row-major, 8KB
    __shared__ unsigned int ArowS[128];

    if (tid < 128) {
        int tok = I[(size_t)be * KCAP + mt * 128 + tid];
        ArowS[tid] = (unsigned)((b * S_ + tok) * D_);
    }
    __syncthreads();

    const int row = tid >> 2;       // staging row 0..63 (sweep 0); +64 (sweep 1)
    const int seg = tid & 3;        // 16B segment within 64B row-slab
    const unsigned aoff0 = ArowS[row]      + seg * 8;
    const unsigned aoff1 = ArowS[row + 64] + seg * 8;
    const size_t   boff0 = ((size_t)e * F_ + nt * 128 + row) * D_ + seg * 8;
    const size_t   boff1 = boff0 + (size_t)64 * D_;

    const int lane = tid & 63;
    const int wv   = tid >> 6;
    const int wm   = (wv & 1) * 64;
    const int wn   = (wv >> 1) * 64;
    const int l15  = lane & 15;
    const int quad = lane >> 4;

    int aoffs[4], boffs[4];
#pragma unroll
    for (int i = 0; i < 4; i++) {
        aoffs[i] = (wm + i * 16 + l15) * 32 + quad * 8;
        boffs[i] = (wn + i * 16 + l15) * 32 + quad * 8;
    }

    floatx4 acc[4][4];
#pragma unroll
    for (int i = 0; i < 4; i++)
#pragma unroll
        for (int j = 0; j < 4; j++) acc[i][j] = (floatx4){0.f, 0.f, 0.f, 0.f};

    for (int k0 = 0; k0 < D_; k0 += 32) {
        gl_lds16(xb  + aoff0 + k0, &Asm[tid * 8]);
        gl_lds16(xb  + aoff1 + k0, &Asm[2048 + tid * 8]);
        gl_lds16(w1t + boff0 + k0, &Bsm[tid * 8]);
        gl_lds16(w1t + boff1 + k0, &Bsm[2048 + tid * 8]);
        __syncthreads();                        // drains vmcnt: LDS tiles complete
        bf16x8 af[4], bfr[4];
#pragma unroll
        for (int i = 0; i < 4; i++) {
            af[i]  = *(const bf16x8*)&Asm[aoffs[i]];
            bfr[i] = *(const bf16x8*)&Bsm[boffs[i]];
        }
#pragma unroll
        for (int i = 0; i < 4; i++)
#pragma unroll
            for (int j = 0; j < 4; j++)
                acc[i][j] = __builtin_amdgcn_mfma_f32_16x16x32_bf16(af[i], bfr[j], acc[i][j], 0, 0, 0);
        __syncthreads();                        // all waves done reading before next stage
    }

    // epilogue: silu -> H (bf16). C/D layout: row = quad*4+r, col = lane&15 (m89-verified)
    unsigned short* Hbe = H + (size_t)be * KCAP * F_;
#pragma unroll
    for (int i = 0; i < 4; i++) {
#pragma unroll
        for (int r = 0; r < 4; r++) {
            int m = mt * 128 + wm + i * 16 + quad * 4 + r;
            unsigned short* hrow = Hbe + (size_t)m * F_ + nt * 128;
#pragma unroll
            for (int j = 0; j < 4; j++) {
                float v = acc[i][j][r];
                float sv = v / (1.f + __expf(-v));
                hrow[wn + j * 16 + l15] = f2b(sv);
            }
        }
    }
}

// ---------------- 6. GEMM2: xmlp[be] = H[be] @ w2[e]  (bf16 out, no atomics) ----------------
__global__ __launch_bounds__(256, 4) void gemm2_kernel(
    const unsigned short* __restrict__ H,    // [B*E][KCAP][F] bf16
    const unsigned short* __restrict__ w2t,  // [E][D][F] bf16
    unsigned short* __restrict__ xmlp)       // [B*E][KCAP][D] bf16
{
    const int be = blockIdx.x >> 4;
    const int t4 = blockIdx.x & 15;
    const int mt = t4 & 1;          // 2 m-tiles
    const int nt = t4 >> 1;         // 8 n-tiles (1024/128)
    const int e  = be & 7;
    const int tid = threadIdx.x;

    __shared__ __align__(16) unsigned short Asm[128 * 32];
    __shared__ __align__(16) unsigned short Bsm[128 * 32];

    const int row = tid >> 2;
    const int seg = tid & 3;
    const size_t aoff0 = ((size_t)be * KCAP + mt * 128 + row) * F_ + seg * 8;
    const size_t aoff1 = aoff0 + (size_t)64 * F_;
    const size_t boff0 = ((size_t)e * D_ + nt * 128 + row) * F_ + seg * 8;
    const size_t boff1 = boff0 + (size_t)64 * F_;

    const int lane = tid & 63;
    const int wv   = tid >> 6;
    const int wm   = (wv & 1) * 64;
    const int wn   = (wv >> 1) * 64;
    const int l15  = lane & 15;
    const int quad = lane >> 4;

    int aoffs[4], boffs[4];
#pragma unroll
    for (int i = 0; i < 4; i++) {
        aoffs[i] = (wm + i * 16 + l15) * 32 + quad * 8;
        boffs[i] = (wn + i * 16 + l15) * 32 + quad * 8;
    }

    floatx4 acc[4][4];
#pragma unroll
    for (int i = 0; i < 4; i++)
#pragma unroll
        for (int j = 0; j < 4; j++) acc[i][j] = (floatx4){0.f, 0.f, 0.f, 0.f};

    for (int k0 = 0; k0 < F_; k0 += 32) {
        gl_lds16(H   + aoff0 + k0, &Asm[tid * 8]);
        gl_lds16(H   + aoff1 + k0, &Asm[2048 + tid * 8]);
        gl_lds16(w2t + boff0 + k0, &Bsm[tid * 8]);
        gl_lds16(w2t + boff1 + k0, &Bsm[2048 + tid * 8]);
        __syncthreads();
        bf16x8 af[4], bfr[4];
#pragma unroll
        for (int i = 0; i < 4; i++) {
            af[i]  = *(const bf16x8*)&Asm[aoffs[i]];
            bfr[i] = *(const bf16x8*)&Bsm[boffs[i]];
        }
#pragma unroll
        for (int i = 0; i < 4; i++)
#pragma unroll
            for (int j = 0; j < 4; j++)
                acc[i][j] = __builtin_amdgcn_mfma_f32_16x16x32_bf16(af[i], bfr[j], acc[i][j], 0, 0, 0);
        __syncthreads();
    }

    // epilogue: plain coalesced bf16 stores (combine kernel applies G and scatters)
    unsigned short* Xbe = xmlp + (size_t)be * KCAP * D_;
#pragma unroll
    for (int i = 0; i < 4; i++) {
#pragma unroll
        for (int r = 0; r < 4; r++) {
            int m = mt * 128 + wm + i * 16 + quad * 4 + r;
            unsigned short* orow = Xbe + (size_t)m * D_ + nt * 128;
#pragma unroll
            for (int j = 0; j < 4; j++)
                orow[wn + j * 16 + l15] = f2b(acc[i][j][r]);
        }
    }
}

// ---------------- 7. combine: out[b,s,:] = sum_e Pmap-hit G * xmlp-row  (every token written once) -----
__global__ void combine_kernel(const unsigned short* __restrict__ xmlp, // [B*E][KCAP][D] bf16
                               const unsigned short* __restrict__ Pmap, // [B][S][E] slot+1
                               const float* __restrict__ G,             // [B*E][KCAP]
                               float* __restrict__ out) {               // [B][S][D] fp32
    int gid  = blockIdx.x * 256 + threadIdx.x;
    int wave = gid >> 6;                               // token id b*S+s, 0..8191
    int lane = gid & 63;
    int b = wave >> 10;
    float acc[16];
#pragma unroll
    for (int i = 0; i < 16; i++) acc[i] = 0.f;
    const unsigned short* pm = Pmap + (size_t)wave * E_;
#pragma unroll
    for (int e = 0; e < E_; e++) {
        int pe = pm[e];                                // wave-uniform scalar load
        if (pe) {
            int beslot = (b * E_ + e) * KCAP + (pe - 1);
            float g = G[beslot];
            const unsigned short* rw = xmlp + (size_t)beslot * D_ + lane * 16;
            ushortx8 r0 = *(const ushortx8*)(rw);
            ushortx8 r1 = *(const ushortx8*)(rw + 8);
#pragma unroll
            for (int i = 0; i < 8; i++) {
                acc[i]     = fmaf(g, b2f(r0[i]), acc[i]);
                acc[8 + i] = fmaf(g, b2f(r1[i]), acc[8 + i]);
            }
        }
    }
    float* orow = out + (size_t)wave * D_ + lane * 16;
    ((float4*)orow)[0] = make_float4(acc[0],  acc[1],  acc[2],  acc[3]);
    ((float4*)orow)[1] = make_float4(acc[4],  acc[5],  acc[6],  acc[7]);
    ((float4*)orow)[2] = make_float4(acc[8],  acc[9],  acc[10], acc[11]);
    ((float4*)orow)[3] = make_float4(acc[12], acc[13], acc[14], acc[15]);
}

// ---------------- launch ----------------
extern "C" void kernel_launch(void* const* d_in, const int* in_sizes, int n_in,
                              void* d_out, int out_size, void* d_ws, size_t ws_size,
                              hipStream_t stream) {
    const float* x  = (const float*)d_in[0];
    const float* cw = (const float*)d_in[1];
    const float* w1 = (const float*)d_in[2];
    const float* w2 = (const float*)d_in[3];
    float* out = (float*)d_out;

    // workspace layout (bytes), total 151,519,232 (round-1 already wrote to byte ~151.4M OK).
    // wT shared between w1t (gemm1) and w2t (gemm2) -- transpose of w2 runs AFTER gemm1.
    char* ws = (char*)d_ws;
    float*          probs = (float*)(ws);                        //   0.26 MB  [B][E][S]
    int*            Ibuf  = (int*)(ws + 262144);                 //  64 KB     [B][E][256]
    float*          Gbuf  = (float*)(ws + 327680);               //  64 KB
    unsigned short* Pmap  = (unsigned short*)(ws + 393216);      // 128 KB     [B][S][E]
    unsigned short* xb    = (unsigned short*)(ws + 524288);      //  16.78 MB  x bf16
    unsigned short* wT    = (unsigned short*)(ws + 17301504);    //  33.55 MB  [E][F][D] then [E][D][F]
    unsigned short* Hbuf  = (unsigned short*)(ws + 50855936);    //  67.11 MB  [B*E][256][F]
    unsigned short* xmlp  = (unsigned short*)(ws + 117964800);   //  33.55 MB  [B*E][256][D]

    hipMemsetAsync(Pmap, 0, (size_t)B_ * S_ * E_ * sizeof(unsigned short), stream);

    router_kernel<<<(B_ * S_ * 64) / 256, 256, 0, stream>>>(x, cw, probs, xb);
    topk_kernel<<<B_ * E_, 256, 0, stream>>>(probs, Ibuf, Gbuf);
    pmap_build_kernel<<<B_ * E_, KCAP, 0, stream>>>(Ibuf, Pmap);
    transpose_cvt_kernel<<<dim3(F_ / 32, D_ / 32, E_), dim3(32, 8), 0, stream>>>(w1, wT, D_, F_);
    gemm1_kernel<<<B_ * E_ * 2 * (F_ / 128), 256, 0, stream>>>(xb, wT, Ibuf, Hbuf);
    transpose_cvt_kernel<<<dim3(D_ / 32, F_ / 32, E_), dim3(32, 8), 0, stream>>>(w2, wT, F_, D_);
    gemm2_kernel<<<B_ * E_ * 2 * (D_ / 128), 256, 0, stream>>>(Hbuf, wT, xmlp);
    combine_kernel<<<(B_ * S_ * 64) / 256, 256, 0, stream>>>(xmlp, Pmap, Gbuf, out);
}